// Round 2
// baseline (170.966 us; speedup 1.0000x reference)
//
#include <hip/hip_runtime.h>
#include <math.h>

#define NN 1024   // nodes
#define KK 256    // in features
#define NH 4      // heads
#define FD 64     // n_hidden
#define HF 256    // NH*FD

// ---------------- GEMM: G = A(1024x256) @ W(256x256) ----------------
// 64x64 tile, 256 threads, 4x4 outputs/thread. z=0: g_l=h@w_l ; z=1: g_r=nei@w_r
__global__ __launch_bounds__(256) void gatv2_gemm(
    const float* __restrict__ h, const float* __restrict__ nei,
    const float* __restrict__ w_l, const float* __restrict__ w_r,
    float* __restrict__ g_l, float* __restrict__ g_r)
{
    const float* A; const float* W; float* G;
    if (blockIdx.z == 0) { A = h;   W = w_l; G = g_l; }
    else                 { A = nei; W = w_r; G = g_r; }

    __shared__ float sA[16][68];   // [k][m], +4 pad
    __shared__ float sW[16][64];   // [k][n]

    const int t   = threadIdx.x;
    const int tm4 = (t >> 4) << 2;   // m-group base (0..60, step 4)
    const int tn4 = (t & 15) << 2;   // n-group base
    const int m0  = blockIdx.y * 64;
    const int n0  = blockIdx.x * 64;

    float acc[4][4] = {};

    const int ar = t >> 2, ac = (t & 3) << 2;   // A-stage: row, 4 k's
    const int wr = t >> 4, wc = (t & 15) << 2;  // W-stage

    for (int k0 = 0; k0 < KK; k0 += 16) {
        float4 va = *(const float4*)&A[(size_t)(m0 + ar)*KK + k0 + ac];
        float4 vw = *(const float4*)&W[(size_t)(k0 + wr)*HF + n0 + wc];
        __syncthreads();
        sA[ac+0][ar] = va.x; sA[ac+1][ar] = va.y;
        sA[ac+2][ar] = va.z; sA[ac+3][ar] = va.w;
        *(float4*)&sW[wr][wc] = vw;
        __syncthreads();
        #pragma unroll
        for (int kk = 0; kk < 16; ++kk) {
            float4 a4 = *(const float4*)&sA[kk][tm4];
            float4 w4 = *(const float4*)&sW[kk][tn4];
            const float am[4] = {a4.x, a4.y, a4.z, a4.w};
            const float wn[4] = {w4.x, w4.y, w4.z, w4.w};
            #pragma unroll
            for (int mi = 0; mi < 4; ++mi)
                #pragma unroll
                for (int ni = 0; ni < 4; ++ni)
                    acc[mi][ni] += am[mi] * wn[ni];
        }
    }
    #pragma unroll
    for (int mi = 0; mi < 4; ++mi)
        *(float4*)&G[(size_t)(m0 + tm4 + mi)*HF + n0 + tn4] =
            make_float4(acc[mi][0], acc[mi][1], acc[mi][2], acc[mi][3]);
}

// ---------------- cl precompute: cl[j,h] = 0.6 * dot(w, g_l[j,h,:]) ----------------
__global__ __launch_bounds__(256) void gatv2_cl(
    const float* __restrict__ g_l, const float* __restrict__ aw, float* __restrict__ cl)
{
    const int idx = blockIdx.x*256 + threadIdx.x;   // j*NH + h
    const int j = idx >> 2, hh = idx & 3;
    const float4* row = (const float4*)(g_l + (size_t)j*HF + hh*FD);
    const float4* wp  = (const float4*)aw;
    float s = 0.f;
    #pragma unroll
    for (int q = 0; q < 16; ++q) {
        float4 g = row[q], w = wp[q];
        s += g.x*w.x + g.y*w.y + g.z*w.z + g.w*w.w;
    }
    cl[idx] = 0.6f * s;
}

// ---------------- Main attention kernel (no LDS, no barriers) ----------------
// grid: (NC j-chunks, 4 i-blocks of 256, 4 heads). Thread owns one i.
// e[i,j] = cr[i] + cl[j] + 0.4 * sum_f w[f]*|g_r[i,f] + g_l[j,f]|
// g_l[j]/g_r[j] rows read at wave-uniform addresses -> expect s_load into SGPRs.
__global__ __launch_bounds__(256, 2) void gatv2_attn(
    const float* __restrict__ g_l, const float* __restrict__ g_r,
    const float* __restrict__ adj, const float* __restrict__ attn_w,
    const float* __restrict__ cl,
    float* __restrict__ accP, float* __restrict__ denP, int JPB)
{
    const int t  = threadIdx.x;
    const int jc = blockIdx.x;
    const int ib = blockIdx.y;
    const int hh = blockIdx.z;
    const int i  = ib*256 + t;

    // raw w -> uniform loads -> SGPRs (no float scaling here: scalar ALU has no fp32)
    const float4* wp = (const float4*)attn_w;

    // own g_r[i] row (per-lane, VGPRs) + raw dot for cr
    float4 gri[16];
    float crdot = 0.f;
    {
        const float4* gp = (const float4*)(g_r + (size_t)i*HF + hh*FD);
        #pragma unroll
        for (int q = 0; q < 16; ++q) {
            float4 g = gp[q], w = wp[q];
            gri[q] = g;
            crdot += w.x*g.x + w.y*g.y + w.z*g.z + w.w*g.w;
        }
    }
    const float cr = 0.6f * crdot;

    float4 acc[16];
    #pragma unroll
    for (int q = 0; q < 16; ++q) acc[q] = make_float4(0.f,0.f,0.f,0.f);
    float denom = 0.f;

    const int jbase = jc * JPB;
    const float* glh = g_l + (size_t)hh*FD;
    const float* grh = g_r + (size_t)hh*FD;

    float mask_next = adj[(size_t)jbase*NN + i];
    for (int jj = 0; jj < JPB; ++jj) {
        const int j = jbase + jj;
        const float mask = mask_next;
        if (jj + 1 < JPB) mask_next = adj[(size_t)(j + 1)*NN + i];
        const float clj = cl[j*NH + hh];                       // uniform -> s_load
        const float4* glr = (const float4*)(glh + (size_t)j*HF);  // uniform row
        float e0 = 0.f, e1 = 0.f, e2 = 0.f, e3 = 0.f;
        #pragma unroll
        for (int q = 0; q < 16; ++q) {   // v_add(s,v) + v_fma(s,abs(v)) per f
            float4 g = glr[q], w = wp[q];
            e0 += w.x * fabsf(g.x + gri[q].x);
            e1 += w.y * fabsf(g.y + gri[q].y);
            e2 += w.z * fabsf(g.z + gri[q].z);
            e3 += w.w * fabsf(g.w + gri[q].w);
        }
        const float e = cr + clj + 0.4f * ((e0+e1) + (e2+e3));
        const float pw = (mask != 0.f) ? __expf(e) : 0.f;
        denom += pw;
        const float4* grr = (const float4*)(grh + (size_t)j*HF);  // uniform row
        #pragma unroll
        for (int q = 0; q < 16; ++q) {
            float4 g = grr[q];
            acc[q].x += pw*g.x; acc[q].y += pw*g.y;
            acc[q].z += pw*g.z; acc[q].w += pw*g.w;
        }
    }
    float* op = accP + (size_t)jc*(NN*HF) + ((size_t)i*NH + hh)*FD;
    #pragma unroll
    for (int q = 0; q < 16; ++q) ((float4*)op)[q] = acc[q];
    denP[(size_t)jc*(NN*NH) + (size_t)i*NH + hh] = denom;
}

// ---------------- Reduce partials + elu ----------------
__global__ __launch_bounds__(256) void gatv2_reduce(
    const float* __restrict__ accP, const float* __restrict__ denP,
    const int* __restrict__ use_elu, float* __restrict__ out, int NC)
{
    const int idx = blockIdx.x*256 + threadIdx.x;   // (i*NH + h)*FD + f
    float s = 0.f, d = 0.f;
    for (int c = 0; c < NC; ++c) {
        s += accP[(size_t)c*(NN*HF) + idx];
        d += denP[(size_t)c*(NN*NH) + (idx >> 6)];
    }
    float r = s / d;
    if (*use_elu != 0) r = (r > 0.f) ? r : expm1f(r);
    out[idx] = r;
}

extern "C" void kernel_launch(void* const* d_in, const int* in_sizes, int n_in,
                              void* d_out, int out_size, void* d_ws, size_t ws_size,
                              hipStream_t stream)
{
    const float* h    = (const float*)d_in[0];
    const float* nei  = (const float*)d_in[1];
    const float* adj  = (const float*)d_in[2];
    const float* w_l  = (const float*)d_in[3];
    const float* w_r  = (const float*)d_in[4];
    const float* aw   = (const float*)d_in[5];
    const int*   uel  = (const int*)d_in[6];
    float* out = (float*)d_out;
    float* ws  = (float*)d_ws;

    float* g_l = ws;
    float* g_r = g_l + (size_t)NN*HF;
    float* cl  = g_r + (size_t)NN*HF;

    // pick j-chunk count by workspace capacity
    int NC = 32;
    while (NC > 1) {
        size_t need = ((size_t)2*NN*HF + (size_t)NN*NH
                     + (size_t)NC*NN*NH + (size_t)NC*NN*HF) * sizeof(float);
        if (need <= ws_size) break;
        NC >>= 1;
    }
    const int JPB = NN / NC;

    float* denP = cl + (size_t)NN*NH;
    float* accP = denP + (size_t)NC*NN*NH;

    hipLaunchKernelGGL(gatv2_gemm, dim3(HF/64, NN/64, 2), dim3(256), 0, stream,
                       h, nei, w_l, w_r, g_l, g_r);
    hipLaunchKernelGGL(gatv2_cl, dim3((NN*NH)/256), dim3(256), 0, stream,
                       g_l, aw, cl);
    hipLaunchKernelGGL(gatv2_attn, dim3(NC, NN/256, NH), dim3(256), 0, stream,
                       g_l, g_r, adj, aw, cl, accP, denP, JPB);
    hipLaunchKernelGGL(gatv2_reduce, dim3((NN*HF)/256), dim3(256), 0, stream,
                       accP, denP, uel, out, NC);
}